// Round 1
// baseline (522.283 us; speedup 1.0000x reference)
//
#include <hip/hip_runtime.h>
#include <math.h>

#define N_NODES 100000
#define LN_EPS 1e-5f

typedef __attribute__((ext_vector_type(8))) short bf16x8;
typedef __attribute__((ext_vector_type(4))) float f32x4;

__device__ __forceinline__ unsigned short f2bf(float f) {
    unsigned int u = __float_as_uint(f);
    return (unsigned short)((u + 0x7FFFu + ((u >> 16) & 1u)) >> 16);
}
__device__ __forceinline__ float bf2f(unsigned short u) {
    return __uint_as_float(((unsigned int)u) << 16);
}

// ---------------- small utility kernels ----------------
__global__ void zero_int(int* __restrict__ p, int n) {
    int i = blockIdx.x * blockDim.x + threadIdx.x;
    if (i < n) p[i] = 0;
}

__global__ void hist_dst(const int* __restrict__ dst, int* __restrict__ deg, int E) {
    int e = blockIdx.x * blockDim.x + threadIdx.x;
    if (e < E) atomicAdd(&deg[dst[e]], 1);
}

// exclusive scan (256/block) + fused dinv = rsqrt(deg+1)
__global__ void scan_block_dinv(const int* __restrict__ in, int* __restrict__ out,
                                int* __restrict__ bsums, float* __restrict__ dinv, int n) {
    __shared__ int s[256];
    int i = blockIdx.x * 256 + threadIdx.x;
    int v = (i < n) ? in[i] : 0;
    s[threadIdx.x] = v;
    __syncthreads();
    for (int off = 1; off < 256; off <<= 1) {
        int t = ((int)threadIdx.x >= off) ? s[threadIdx.x - off] : 0;
        __syncthreads();
        s[threadIdx.x] += t;
        __syncthreads();
    }
    if (i < n) {
        out[i] = s[threadIdx.x] - v;  // exclusive
        dinv[i] = rsqrtf((float)v + 1.f);
    }
    if (threadIdx.x == 255) bsums[blockIdx.x] = s[255];
}

// parallel exclusive scan of block sums (nb <= 512) + set offsets[N]=E
__global__ void scan_sums_p(int* __restrict__ bsums, int nb, int* __restrict__ off_end, int Ev) {
    __shared__ int s[512];
    int i = threadIdx.x;
    int v = (i < nb) ? bsums[i] : 0;
    s[i] = v;
    __syncthreads();
    for (int off = 1; off < 512; off <<= 1) {
        int t = (i >= off) ? s[i - off] : 0;
        __syncthreads();
        s[i] += t;
        __syncthreads();
    }
    if (i < nb) bsums[i] = s[i] - v;
    if (i == 0) *off_end = Ev;
}

// finalize offsets AND init cursor=offsets AND init per-region bucket tails
// tails[r] = offsets[12500*r] (regions are contiguous node ranges of the
// dst-sorted CSR, so region r's bucket slab is exactly [off[12500r], off[12500(r+1)]))
__global__ void scan_add_copy(int* __restrict__ out, int* __restrict__ cursor,
                              const int* __restrict__ bsums, int* __restrict__ tails, int n) {
    int i = blockIdx.x * 256 + threadIdx.x;
    if (i < n) {
        int v = out[i] + bsums[blockIdx.x];
        out[i] = v;
        cursor[i] = v;
        if (i % 12500 == 0) tails[i / 12500] = v;
    }
}

// ---- CSR fill, phase A: bucket edges by dst-region (coalesced read + append write) ----
// Replaces the old 8x-replicated fill_csr_xcd whose counters showed
// FETCH = 8 x dst (49.9MB) and WRITE = 11x csr (74MB, ~46B HBM per 4B store).
// Each block: LDS-count its 8192 edges per region, reserve a contiguous slab
// per region with ONE global atomic, then append (src,dst) pairs. All global
// writes are contiguous 8B within disjoint slabs -> no line ping-pong.
__global__ void bucket_edges(const int* __restrict__ src, const int* __restrict__ dst,
                             int* __restrict__ tails, uint2* __restrict__ bucket, int E) {
    __shared__ int cnt[8];
    __shared__ int pos[8];
    int t = threadIdx.x;
    if (t < 8) cnt[t] = 0;
    __syncthreads();
    int e0 = blockIdx.x * 8192;
#pragma unroll 4
    for (int i = 0; i < 32; ++i) {
        int e = e0 + i * 256 + t;
        if (e < E) {
            unsigned d = (unsigned)dst[e];
            atomicAdd(&cnt[d / 12500u], 1);
        }
    }
    __syncthreads();
    if (t < 8) pos[t] = atomicAdd(&tails[t], cnt[t]);
    __syncthreads();
#pragma unroll 4
    for (int i = 0; i < 32; ++i) {
        int e = e0 + i * 256 + t;
        if (e < E) {
            unsigned s = (unsigned)src[e];         // chunk is L2-hot from pass 1
            unsigned d = (unsigned)dst[e];
            int p = atomicAdd(&pos[d / 12500u], 1);
            bucket[p] = make_uint2(s, d);
        }
    }
}

// ---- CSR fill, phase B: region-pinned scatter (reads coalesced, scatter L2-local) ----
// blockIdx&7 ~ XCD; each region's csr window (~800KB) + cursor window (50KB)
// fit in that XCD's 4MB L2, so the 4B scattered stores coalesce in L2.
__global__ void fill_bucket(const uint2* __restrict__ bucket, const int* __restrict__ offsets,
                            int* __restrict__ cursor, int* __restrict__ csr) {
    int r = blockIdx.x & 7;
    int cid = blockIdx.x >> 3;
    int nch = gridDim.x >> 3;
    int s0 = offsets[r * 12500];
    int s1 = offsets[(r + 1) * 12500];  // r==7 -> offsets[N] == E
    for (int e = s0 + cid * 256 + (int)threadIdx.x; e < s1; e += nch * 256) {
        uint2 ed = bucket[e];
        int p = atomicAdd(&cursor[ed.y], 1);
        csr[p] = (int)ed.x;
    }
}

// ---------------- MFMA bf16 gemm: Y = X[n,K] @ W[K,OUT] (+bias, +LN+ELU) ----------------
template <int K, int OUT, bool LN, bool BIAS, bool AF32, bool OF32>
__launch_bounds__(256)
__global__ void mfma_gemm(const void* __restrict__ Xv, const float* __restrict__ W,
                          const float* __restrict__ bias, const float* __restrict__ gamma,
                          const float* __restrict__ beta, void* __restrict__ Yv, int n) {
    constexpr int T  = OUT / 16;
    constexpr int KP = K + 8;

    __shared__ __align__(16) unsigned short sWT[OUT * KP];  // W^T bf16
    for (int i = threadIdx.x; i < K * OUT; i += 256) {
        int k = i / OUT, o = i - k * OUT;
        sWT[o * KP + k] = f2bf(W[i]);
    }
    __syncthreads();

    int wv = threadIdx.x >> 6, lane = threadIdx.x & 63;
    int quad = lane >> 4, l16 = lane & 15;
    int m0 = (blockIdx.x * 4 + wv) * 16;
    int rowc = min(m0 + l16, n - 1);

    f32x4 acc[T];
#pragma unroll
    for (int t = 0; t < T; ++t) acc[t] = (f32x4){0.f, 0.f, 0.f, 0.f};

#pragma unroll
    for (int s = 0; s < K / 32; ++s) {
        int koff = s * 32 + quad * 8;
        bf16x8 af;
        if (AF32) {
            const float4* X4 = (const float4*)Xv;
            size_t base = ((size_t)rowc * K + koff) >> 2;
            float4 a0 = X4[base];
            float4 a1 = X4[base + 1];
            af[0] = (short)f2bf(a0.x); af[1] = (short)f2bf(a0.y);
            af[2] = (short)f2bf(a0.z); af[3] = (short)f2bf(a0.w);
            af[4] = (short)f2bf(a1.x); af[5] = (short)f2bf(a1.y);
            af[6] = (short)f2bf(a1.z); af[7] = (short)f2bf(a1.w);
        } else {
            const unsigned short* Xb = (const unsigned short*)Xv;
            af = *(const bf16x8*)(Xb + (size_t)rowc * K + koff);
        }
#pragma unroll
        for (int t = 0; t < T; ++t) {
            const bf16x8 bfrag = *(const bf16x8*)&sWT[(t * 16 + l16) * KP + koff];
            acc[t] = __builtin_amdgcn_mfma_f32_16x16x32_bf16(af, bfrag, acc[t], 0, 0, 0);
        }
    }

    float bj[T], gj[T], btj[T];
#pragma unroll
    for (int t = 0; t < T; ++t) {
        int c = t * 16 + l16;
        bj[t]  = BIAS ? bias[c] : 0.f;
        gj[t]  = LN ? gamma[c] : 1.f;
        btj[t] = LN ? beta[c] : 0.f;
    }

    float* Yf = (float*)Yv;
    unsigned short* Yb = (unsigned short*)Yv;

    if (LN) {
        float s[4] = {0.f, 0.f, 0.f, 0.f}, sq[4] = {0.f, 0.f, 0.f, 0.f};
#pragma unroll
        for (int t = 0; t < T; ++t)
#pragma unroll
            for (int r = 0; r < 4; ++r) {
                float v = acc[t][r] + bj[t];
                s[r] += v;
                sq[r] += v * v;
            }
#pragma unroll
        for (int off = 1; off < 16; off <<= 1)
#pragma unroll
            for (int r = 0; r < 4; ++r) {
                s[r] += __shfl_xor(s[r], off, 64);
                sq[r] += __shfl_xor(sq[r], off, 64);
            }
        float mu[4], rs[4];
#pragma unroll
        for (int r = 0; r < 4; ++r) {
            mu[r] = s[r] / OUT;
            float var = sq[r] / OUT - mu[r] * mu[r];
            rs[r] = rsqrtf(var + LN_EPS);
        }
#pragma unroll
        for (int r = 0; r < 4; ++r) {
            int rowg = m0 + quad * 4 + r;
            if (rowg < n) {
#pragma unroll
                for (int t = 0; t < T; ++t) {
                    float y = (acc[t][r] + bj[t] - mu[r]) * rs[r] * gj[t] + btj[t];
                    y = y > 0.f ? y : expm1f(y);
                    size_t idx = (size_t)rowg * OUT + t * 16 + l16;
                    if (OF32) Yf[idx] = y; else Yb[idx] = f2bf(y);
                }
            }
        }
    } else {
#pragma unroll
        for (int r = 0; r < 4; ++r) {
            int rowg = m0 + quad * 4 + r;
            if (rowg < n) {
#pragma unroll
                for (int t = 0; t < T; ++t) {
                    float y = acc[t][r] + bj[t];
                    size_t idx = (size_t)rowg * OUT + t * 16 + l16;
                    if (OF32) Yf[idx] = y; else Yb[idx] = f2bf(y);
                }
            }
        }
    }
}

// ---------------- fused gather v2: 4 edges per wave-load (ushort4/lane) ----------------
template <bool LN>
__global__ void gather64(const unsigned short* __restrict__ xw, const int* __restrict__ offsets,
                         const int* __restrict__ csr_src, const float* __restrict__ dinv,
                         const float* __restrict__ bias, const float* __restrict__ gamma,
                         const float* __restrict__ beta, unsigned short* __restrict__ out, int n) {
    int wave = threadIdx.x >> 6;
    int lane = threadIdx.x & 63;
    int node = blockIdx.x * (blockDim.x >> 6) + wave;
    if (node >= n) return;
    int beg = offsets[node], end = offsets[node + 1];
    int quad = lane >> 4, q16 = lane & 15;
    int c0 = q16 * 4;

    float a0 = 0.f, a1 = 0.f, a2 = 0.f, a3 = 0.f;
    for (int base = beg; base < end; base += 64) {
        int m = min(64, end - base);
        int myS = (lane < m) ? csr_src[base + lane] : 0;
        float myN = (lane < m) ? dinv[myS] : 0.f;  // 0-weight for pad lanes
#pragma unroll 4
        for (int j4 = 0; j4 < m; j4 += 4) {
            int e = j4 + quad;
            int s = __shfl(myS, e, 64);
            float nm = __shfl(myN, e, 64);
            ushort4 r = *(const ushort4*)(xw + (size_t)s * 64 + c0);
            a0 += bf2f(r.x) * nm;
            a1 += bf2f(r.y) * nm;
            a2 += bf2f(r.z) * nm;
            a3 += bf2f(r.w) * nm;
        }
    }
    a0 += __shfl_xor(a0, 16, 64); a0 += __shfl_xor(a0, 32, 64);
    a1 += __shfl_xor(a1, 16, 64); a1 += __shfl_xor(a1, 32, 64);
    a2 += __shfl_xor(a2, 16, 64); a2 += __shfl_xor(a2, 32, 64);
    a3 += __shfl_xor(a3, 16, 64); a3 += __shfl_xor(a3, 32, 64);

    float dd = dinv[node];
    ushort4 sr = *(const ushort4*)(xw + (size_t)node * 64 + c0);
    float y0 = a0 * dd + bf2f(sr.x) * dd * dd;
    float y1 = a1 * dd + bf2f(sr.y) * dd * dd;
    float y2 = a2 * dd + bf2f(sr.z) * dd * dd;
    float y3 = a3 * dd + bf2f(sr.w) * dd * dd;

    if (!LN) {
        if (quad == 0) {
            ushort4 o;
            o.x = f2bf(y0); o.y = f2bf(y1); o.z = f2bf(y2); o.w = f2bf(y3);
            *(ushort4*)(out + (size_t)node * 64 + c0) = o;
        }
        return;
    }
    float4 bv = *(const float4*)(bias + c0);
    float4 gv = *(const float4*)(gamma + c0);
    float4 tv = *(const float4*)(beta + c0);
    y0 += bv.x; y1 += bv.y; y2 += bv.z; y3 += bv.w;
    float s = y0 + y1 + y2 + y3;
    float sq = y0 * y0 + y1 * y1 + y2 * y2 + y3 * y3;
#pragma unroll
    for (int off = 1; off < 16; off <<= 1) {
        s += __shfl_xor(s, off, 64);
        sq += __shfl_xor(sq, off, 64);
    }
    float mu = s / 64.f;
    float var = sq / 64.f - mu * mu;
    float rs = rsqrtf(var + LN_EPS);
    float z0 = (y0 - mu) * rs * gv.x + tv.x; z0 = z0 > 0.f ? z0 : expm1f(z0);
    float z1 = (y1 - mu) * rs * gv.y + tv.y; z1 = z1 > 0.f ? z1 : expm1f(z1);
    float z2 = (y2 - mu) * rs * gv.z + tv.z; z2 = z2 > 0.f ? z2 : expm1f(z2);
    float z3 = (y3 - mu) * rs * gv.w + tv.w; z3 = z3 > 0.f ? z3 : expm1f(z3);
    if (quad == 0) {
        ushort4 o;
        o.x = f2bf(z0); o.y = f2bf(z1); o.z = f2bf(z2); o.w = f2bf(z3);
        *(ushort4*)(out + (size_t)node * 64 + c0) = o;
    }
}

extern "C" void kernel_launch(void* const* d_in, const int* in_sizes, int n_in,
                              void* d_out, int out_size, void* d_ws, size_t ws_size,
                              hipStream_t stream) {
    const float* x  = (const float*)d_in[0];
    const int* ei   = (const int*)d_in[1];
    const float* W1 = (const float*)d_in[2];
    const float* b1 = (const float*)d_in[3];
    const float* g1 = (const float*)d_in[4];
    const float* be1= (const float*)d_in[5];
    const float* W2 = (const float*)d_in[6];
    const float* b2 = (const float*)d_in[7];
    const float* g2 = (const float*)d_in[8];
    const float* be2= (const float*)d_in[9];
    const float* W3 = (const float*)d_in[10];
    const float* b3 = (const float*)d_in[11];
    const float* g3 = (const float*)d_in[12];
    const float* be3= (const float*)d_in[13];
    const float* lw1= (const float*)d_in[14];
    const float* lb1= (const float*)d_in[15];
    const float* g4 = (const float*)d_in[16];
    const float* be4= (const float*)d_in[17];
    const float* lw2= (const float*)d_in[18];
    const float* lb2= (const float*)d_in[19];
    float* out = (float*)d_out;

    const int E = in_sizes[1] / 2;
    const int* src = ei;
    const int* dst = ei + E;
    const int N = N_NODES;

    // workspace layout (intermediates in bf16)
    unsigned short* bufA = (unsigned short*)d_ws;       // N*128 bf16
    unsigned short* bufB = bufA + (size_t)N * 128;      // N*128 bf16
    float* dinv    = (float*)(bufB + (size_t)N * 128);  // N f32
    int*   deg     = (int*)(dinv + N);                  // N
    int*   offsets = deg + N;                           // N+1
    int*   cursor  = offsets + N + 1;                   // N
    int*   csr     = cursor + N;                        // E
    int*   bsums   = csr + E;                           // 512
    int*   tails   = bsums + 512;                       // 8 (bucket append tails)
    // bucket aliases bufB: E*8B = 12.8MB <= 25.6MB, and bufB is dead until
    // gather1 writes it (strictly after fill_bucket in stream order).
    uint2* bucket  = (uint2*)bufB;

    auto cdiv = [](long long a, long long b) { return (int)((a + b - 1) / b); };
    const int NB = cdiv(N, 256);
    const int GB = cdiv(N, 64);  // mfma gemm grid (64 rows/block)

    // ---- build CSR (dst-sorted) + dinv ----
    zero_int<<<NB, 256, 0, stream>>>(deg, N);
    hist_dst<<<cdiv(E, 256), 256, 0, stream>>>(dst, deg, E);
    scan_block_dinv<<<NB, 256, 0, stream>>>(deg, offsets, bsums, dinv, N);
    scan_sums_p<<<1, 512, 0, stream>>>(bsums, NB, offsets + N, E);
    scan_add_copy<<<NB, 256, 0, stream>>>(offsets, cursor, bsums, tails, N);
    // two-phase fill: region-bucket (coalesced) then XCD-pinned L2-local scatter
    bucket_edges<<<cdiv(E, 8192), 256, 0, stream>>>(src, dst, tails, bucket, E);
    fill_bucket<<<8 * cdiv(E, 8 * 1024), 256, 0, stream>>>(bucket, offsets, cursor, csr);

    // ---- Layer 1: xw1 = x @ W1 (128->64, fp32 in); h1 = LN_ELU(gather + b1) ----
    mfma_gemm<128, 64, false, false, true, false><<<GB, 256, 0, stream>>>(
        x, W1, nullptr, nullptr, nullptr, bufA, N);
    gather64<true><<<cdiv(N, 4), 256, 0, stream>>>(bufA, offsets, csr, dinv, b1, g1, be1, bufB, N);

    // ---- Layer 2 (aggregate-first): a2 = gather(h1); h2 = LN_ELU(a2 @ W2 + b2) ----
    gather64<false><<<cdiv(N, 4), 256, 0, stream>>>(bufB, offsets, csr, dinv, nullptr, nullptr, nullptr, bufA, N);
    mfma_gemm<64, 128, true, true, false, false><<<GB, 256, 0, stream>>>(
        bufA, W2, b2, g2, be2, bufB, N);

    // ---- Layer 3: xw3 = h2 @ W3 (128->64); h3 = LN_ELU(gather + b3) ----
    mfma_gemm<128, 64, false, false, false, false><<<GB, 256, 0, stream>>>(
        bufB, W3, nullptr, nullptr, nullptr, bufA, N);
    gather64<true><<<cdiv(N, 4), 256, 0, stream>>>(bufA, offsets, csr, dinv, b3, g3, be3, bufB, N);

    // ---- lin1: t = LN_ELU(h3 @ lw1 + lb1) (64->32) ----
    mfma_gemm<64, 32, true, true, false, false><<<GB, 256, 0, stream>>>(
        bufB, lw1, lb1, g4, be4, bufA, N);

    // ---- lin2: out = t @ lw2 + lb2 (32->32, fp32 out) ----
    mfma_gemm<32, 32, false, true, false, true><<<GB, 256, 0, stream>>>(
        bufA, lw2, lb2, nullptr, nullptr, out, N);
}

// Round 2
// 389.360 us; speedup vs baseline: 1.3414x; 1.3414x over previous
//
#include <hip/hip_runtime.h>
#include <math.h>

#define N_NODES 100000
#define LN_EPS 1e-5f
#define NBUCK ((N_NODES + 255) / 256)  // 391 buckets of 256 nodes
#define EPB 8192                        // edges per block in count/place

typedef __attribute__((ext_vector_type(8))) short bf16x8;
typedef __attribute__((ext_vector_type(4))) float f32x4;

__device__ __forceinline__ unsigned short f2bf(float f) {
    unsigned int u = __float_as_uint(f);
    return (unsigned short)((u + 0x7FFFu + ((u >> 16) & 1u)) >> 16);
}
__device__ __forceinline__ float bf2f(unsigned short u) {
    return __uint_as_float(((unsigned int)u) << 16);
}

// ======== atomic-free CSR build (counting sort by 256-node bucket) ========
// R1 counters: E global-scope atomicAdd + scattered 4B stores cost ~42B HBM
// write per edge (67-74MB for a 6.4MB output) no matter the XCD locality —
// device-scope atomics resolve past L2. So: deterministic placement, all
// conflict resolution in LDS.

// K1: per-block histogram of dst buckets -> counts[blk][bucket]
__global__ void count_edges(const int* __restrict__ dst, int* __restrict__ counts, int E) {
    __shared__ int hist[NBUCK];
    for (int b = threadIdx.x; b < NBUCK; b += 512) hist[b] = 0;
    __syncthreads();
    int e0 = blockIdx.x * EPB;
#pragma unroll 4
    for (int i = 0; i < EPB / 512; ++i) {
        int e = e0 + i * 512 + (int)threadIdx.x;
        if (e < E) atomicAdd(&hist[((unsigned)dst[e]) >> 8], 1);
    }
    __syncthreads();
    for (int b = threadIdx.x; b < NBUCK; b += 512)
        counts[blockIdx.x * NBUCK + b] = hist[b];
}

// K2: per-bucket exclusive scan across blocks -> pos[blk][bucket], tot[bucket]
// (NBLK <= 512 holds for E <= 4.2M)
__global__ void scan_pos(const int* __restrict__ counts, int* __restrict__ pos,
                         int* __restrict__ tot, int nblk) {
    __shared__ int s[512];
    int b = blockIdx.x, i = threadIdx.x;
    int v = (i < nblk) ? counts[i * NBUCK + b] : 0;
    s[i] = v;
    __syncthreads();
    for (int off = 1; off < 512; off <<= 1) {
        int t = (i >= off) ? s[i - off] : 0;
        __syncthreads();
        s[i] += t;
        __syncthreads();
    }
    if (i < nblk) pos[i * NBUCK + b] = s[i] - v;
    if (i == 511) tot[b] = s[511];
}

// K3: exclusive scan of bucket totals -> base[bucket], base[NBUCK]=E
__global__ void scan_base(const int* __restrict__ tot, int* __restrict__ base, int E) {
    __shared__ int s[512];
    int i = threadIdx.x;
    int v = (i < NBUCK) ? tot[i] : 0;
    s[i] = v;
    __syncthreads();
    for (int off = 1; off < 512; off <<= 1) {
        int t = (i >= off) ? s[i - off] : 0;
        __syncthreads();
        s[i] += t;
        __syncthreads();
    }
    if (i < NBUCK) base[i] = s[i] - v;
    if (i == 0) base[NBUCK] = E;
}

// K4: place edges into per-(block,bucket) disjoint slabs via LDS cursors.
// Packed entry: (dst&255)<<24 | src  (src < 2^17 < 2^24) -> 4B/edge.
__global__ void place_edges(const int* __restrict__ src, const int* __restrict__ dst,
                            const int* __restrict__ pos, const int* __restrict__ base,
                            unsigned* __restrict__ bucket, int E) {
    __shared__ int lcur[NBUCK];
    for (int b = threadIdx.x; b < NBUCK; b += 512)
        lcur[b] = pos[blockIdx.x * NBUCK + b] + base[b];
    __syncthreads();
    int e0 = blockIdx.x * EPB;
#pragma unroll 4
    for (int i = 0; i < EPB / 512; ++i) {
        int e = e0 + i * 512 + (int)threadIdx.x;
        if (e < E) {
            unsigned d = (unsigned)dst[e];
            unsigned s = (unsigned)src[e];
            int p = atomicAdd(&lcur[d >> 8], 1);
            bucket[p] = ((d & 255u) << 24) | s;
        }
    }
}

// K5: one block per bucket: slab histogram -> degree/dinv/offsets (fused),
// then scatter csr within the block's private 16KB window via LDS cursors.
__global__ void build_csr_node(const unsigned* __restrict__ bucket, const int* __restrict__ base,
                               int* __restrict__ offsets, float* __restrict__ dinv,
                               int* __restrict__ csr, int E) {
    __shared__ int hist[256];
    __shared__ int cur[256];
    int b = blockIdx.x, t = threadIdx.x;
    int r0 = b << 8;
    hist[t] = 0;
    __syncthreads();
    int s0 = base[b], s1 = base[b + 1];
    for (int e = s0 + t; e < s1; e += 256)
        atomicAdd(&hist[bucket[e] >> 24], 1);
    __syncthreads();
    int deg = hist[t];
    for (int off = 1; off < 256; off <<= 1) {
        int tv = (t >= off) ? hist[t - off] : 0;
        __syncthreads();
        hist[t] += tv;
        __syncthreads();
    }
    int excl = hist[t] - deg;  // exclusive scan within bucket
    int node = r0 + t;
    if (node < N_NODES) {
        offsets[node] = s0 + excl;
        dinv[node] = rsqrtf((float)deg + 1.f);
        cur[t] = s0 + excl;
    }
    if (node == N_NODES - 1) offsets[N_NODES] = E;
    __syncthreads();
    for (int e = s0 + t; e < s1; e += 256) {
        unsigned u = bucket[e];
        int p = atomicAdd(&cur[u >> 24], 1);  // LDS atomic, window is L1/L2-hot
        csr[p] = (int)(u & 0xFFFFFFu);
    }
}

// ---------------- MFMA bf16 gemm: Y = X[n,K] @ W[K,OUT] (+bias, +LN+ELU) ----------------
template <int K, int OUT, bool LN, bool BIAS, bool AF32, bool OF32>
__launch_bounds__(256)
__global__ void mfma_gemm(const void* __restrict__ Xv, const float* __restrict__ W,
                          const float* __restrict__ bias, const float* __restrict__ gamma,
                          const float* __restrict__ beta, void* __restrict__ Yv, int n) {
    constexpr int T  = OUT / 16;
    constexpr int KP = K + 8;

    __shared__ __align__(16) unsigned short sWT[OUT * KP];  // W^T bf16
    for (int i = threadIdx.x; i < K * OUT; i += 256) {
        int k = i / OUT, o = i - k * OUT;
        sWT[o * KP + k] = f2bf(W[i]);
    }
    __syncthreads();

    int wv = threadIdx.x >> 6, lane = threadIdx.x & 63;
    int quad = lane >> 4, l16 = lane & 15;
    int m0 = (blockIdx.x * 4 + wv) * 16;
    int rowc = min(m0 + l16, n - 1);

    f32x4 acc[T];
#pragma unroll
    for (int t = 0; t < T; ++t) acc[t] = (f32x4){0.f, 0.f, 0.f, 0.f};

#pragma unroll
    for (int s = 0; s < K / 32; ++s) {
        int koff = s * 32 + quad * 8;
        bf16x8 af;
        if (AF32) {
            const float4* X4 = (const float4*)Xv;
            size_t base = ((size_t)rowc * K + koff) >> 2;
            float4 a0 = X4[base];
            float4 a1 = X4[base + 1];
            af[0] = (short)f2bf(a0.x); af[1] = (short)f2bf(a0.y);
            af[2] = (short)f2bf(a0.z); af[3] = (short)f2bf(a0.w);
            af[4] = (short)f2bf(a1.x); af[5] = (short)f2bf(a1.y);
            af[6] = (short)f2bf(a1.z); af[7] = (short)f2bf(a1.w);
        } else {
            const unsigned short* Xb = (const unsigned short*)Xv;
            af = *(const bf16x8*)(Xb + (size_t)rowc * K + koff);
        }
#pragma unroll
        for (int t = 0; t < T; ++t) {
            const bf16x8 bfrag = *(const bf16x8*)&sWT[(t * 16 + l16) * KP + koff];
            acc[t] = __builtin_amdgcn_mfma_f32_16x16x32_bf16(af, bfrag, acc[t], 0, 0, 0);
        }
    }

    float bj[T], gj[T], btj[T];
#pragma unroll
    for (int t = 0; t < T; ++t) {
        int c = t * 16 + l16;
        bj[t]  = BIAS ? bias[c] : 0.f;
        gj[t]  = LN ? gamma[c] : 1.f;
        btj[t] = LN ? beta[c] : 0.f;
    }

    float* Yf = (float*)Yv;
    unsigned short* Yb = (unsigned short*)Yv;

    if (LN) {
        float s[4] = {0.f, 0.f, 0.f, 0.f}, sq[4] = {0.f, 0.f, 0.f, 0.f};
#pragma unroll
        for (int t = 0; t < T; ++t)
#pragma unroll
            for (int r = 0; r < 4; ++r) {
                float v = acc[t][r] + bj[t];
                s[r] += v;
                sq[r] += v * v;
            }
#pragma unroll
        for (int off = 1; off < 16; off <<= 1)
#pragma unroll
            for (int r = 0; r < 4; ++r) {
                s[r] += __shfl_xor(s[r], off, 64);
                sq[r] += __shfl_xor(sq[r], off, 64);
            }
        float mu[4], rs[4];
#pragma unroll
        for (int r = 0; r < 4; ++r) {
            mu[r] = s[r] / OUT;
            float var = sq[r] / OUT - mu[r] * mu[r];
            rs[r] = rsqrtf(var + LN_EPS);
        }
#pragma unroll
        for (int r = 0; r < 4; ++r) {
            int rowg = m0 + quad * 4 + r;
            if (rowg < n) {
#pragma unroll
                for (int t = 0; t < T; ++t) {
                    float y = (acc[t][r] + bj[t] - mu[r]) * rs[r] * gj[t] + btj[t];
                    y = y > 0.f ? y : expm1f(y);
                    size_t idx = (size_t)rowg * OUT + t * 16 + l16;
                    if (OF32) Yf[idx] = y; else Yb[idx] = f2bf(y);
                }
            }
        }
    } else {
#pragma unroll
        for (int r = 0; r < 4; ++r) {
            int rowg = m0 + quad * 4 + r;
            if (rowg < n) {
#pragma unroll
                for (int t = 0; t < T; ++t) {
                    float y = acc[t][r] + bj[t];
                    size_t idx = (size_t)rowg * OUT + t * 16 + l16;
                    if (OF32) Yf[idx] = y; else Yb[idx] = f2bf(y);
                }
            }
        }
    }
}

// ---------------- fused gather v2: 4 edges per wave-load (ushort4/lane) ----------------
template <bool LN>
__global__ void gather64(const unsigned short* __restrict__ xw, const int* __restrict__ offsets,
                         const int* __restrict__ csr_src, const float* __restrict__ dinv,
                         const float* __restrict__ bias, const float* __restrict__ gamma,
                         const float* __restrict__ beta, unsigned short* __restrict__ out, int n) {
    int wave = threadIdx.x >> 6;
    int lane = threadIdx.x & 63;
    int node = blockIdx.x * (blockDim.x >> 6) + wave;
    if (node >= n) return;
    int beg = offsets[node], end = offsets[node + 1];
    int quad = lane >> 4, q16 = lane & 15;
    int c0 = q16 * 4;

    float a0 = 0.f, a1 = 0.f, a2 = 0.f, a3 = 0.f;
    for (int base = beg; base < end; base += 64) {
        int m = min(64, end - base);
        int myS = (lane < m) ? csr_src[base + lane] : 0;
        float myN = (lane < m) ? dinv[myS] : 0.f;  // 0-weight for pad lanes
#pragma unroll 4
        for (int j4 = 0; j4 < m; j4 += 4) {
            int e = j4 + quad;
            int s = __shfl(myS, e, 64);
            float nm = __shfl(myN, e, 64);
            ushort4 r = *(const ushort4*)(xw + (size_t)s * 64 + c0);
            a0 += bf2f(r.x) * nm;
            a1 += bf2f(r.y) * nm;
            a2 += bf2f(r.z) * nm;
            a3 += bf2f(r.w) * nm;
        }
    }
    a0 += __shfl_xor(a0, 16, 64); a0 += __shfl_xor(a0, 32, 64);
    a1 += __shfl_xor(a1, 16, 64); a1 += __shfl_xor(a1, 32, 64);
    a2 += __shfl_xor(a2, 16, 64); a2 += __shfl_xor(a2, 32, 64);
    a3 += __shfl_xor(a3, 16, 64); a3 += __shfl_xor(a3, 32, 64);

    float dd = dinv[node];
    ushort4 sr = *(const ushort4*)(xw + (size_t)node * 64 + c0);
    float y0 = a0 * dd + bf2f(sr.x) * dd * dd;
    float y1 = a1 * dd + bf2f(sr.y) * dd * dd;
    float y2 = a2 * dd + bf2f(sr.z) * dd * dd;
    float y3 = a3 * dd + bf2f(sr.w) * dd * dd;

    if (!LN) {
        if (quad == 0) {
            ushort4 o;
            o.x = f2bf(y0); o.y = f2bf(y1); o.z = f2bf(y2); o.w = f2bf(y3);
            *(ushort4*)(out + (size_t)node * 64 + c0) = o;
        }
        return;
    }
    float4 bv = *(const float4*)(bias + c0);
    float4 gv = *(const float4*)(gamma + c0);
    float4 tv = *(const float4*)(beta + c0);
    y0 += bv.x; y1 += bv.y; y2 += bv.z; y3 += bv.w;
    float s = y0 + y1 + y2 + y3;
    float sq = y0 * y0 + y1 * y1 + y2 * y2 + y3 * y3;
#pragma unroll
    for (int off = 1; off < 16; off <<= 1) {
        s += __shfl_xor(s, off, 64);
        sq += __shfl_xor(sq, off, 64);
    }
    float mu = s / 64.f;
    float var = sq / 64.f - mu * mu;
    float rs = rsqrtf(var + LN_EPS);
    float z0 = (y0 - mu) * rs * gv.x + tv.x; z0 = z0 > 0.f ? z0 : expm1f(z0);
    float z1 = (y1 - mu) * rs * gv.y + tv.y; z1 = z1 > 0.f ? z1 : expm1f(z1);
    float z2 = (y2 - mu) * rs * gv.z + tv.z; z2 = z2 > 0.f ? z2 : expm1f(z2);
    float z3 = (y3 - mu) * rs * gv.w + tv.w; z3 = z3 > 0.f ? z3 : expm1f(z3);
    if (quad == 0) {
        ushort4 o;
        o.x = f2bf(z0); o.y = f2bf(z1); o.z = f2bf(z2); o.w = f2bf(z3);
        *(ushort4*)(out + (size_t)node * 64 + c0) = o;
    }
}

extern "C" void kernel_launch(void* const* d_in, const int* in_sizes, int n_in,
                              void* d_out, int out_size, void* d_ws, size_t ws_size,
                              hipStream_t stream) {
    const float* x  = (const float*)d_in[0];
    const int* ei   = (const int*)d_in[1];
    const float* W1 = (const float*)d_in[2];
    const float* b1 = (const float*)d_in[3];
    const float* g1 = (const float*)d_in[4];
    const float* be1= (const float*)d_in[5];
    const float* W2 = (const float*)d_in[6];
    const float* b2 = (const float*)d_in[7];
    const float* g2 = (const float*)d_in[8];
    const float* be2= (const float*)d_in[9];
    const float* W3 = (const float*)d_in[10];
    const float* b3 = (const float*)d_in[11];
    const float* g3 = (const float*)d_in[12];
    const float* be3= (const float*)d_in[13];
    const float* lw1= (const float*)d_in[14];
    const float* lb1= (const float*)d_in[15];
    const float* g4 = (const float*)d_in[16];
    const float* be4= (const float*)d_in[17];
    const float* lw2= (const float*)d_in[18];
    const float* lb2= (const float*)d_in[19];
    float* out = (float*)d_out;

    const int E = in_sizes[1] / 2;
    const int* src = ei;
    const int* dst = ei + E;
    const int N = N_NODES;

    // workspace layout (intermediates in bf16)
    unsigned short* bufA = (unsigned short*)d_ws;       // N*128 bf16
    unsigned short* bufB = bufA + (size_t)N * 128;      // N*128 bf16
    float* dinv    = (float*)(bufB + (size_t)N * 128);  // N f32
    int*   offsets = (int*)(dinv + N);                  // N+1
    int*   csr     = offsets + N + 1;                   // E
    int*   tot     = csr + E;                           // NBUCK
    int*   base    = tot + NBUCK;                       // NBUCK+1

    auto cdiv = [](long long a, long long b) { return (int)((a + b - 1) / b); };
    const int NBLK = cdiv(E, EPB);  // 196 for E=1.6M (must be <= 512)

    // counts/pos alias bufA (dead until gemm1); bucket aliases bufB (dead until
    // gather1 writes it). All CSR-build kernels finish before either is reused.
    int* counts = (int*)bufA;                 // NBLK*NBUCK ints (~300KB)
    int* pos    = counts + (size_t)NBLK * NBUCK;
    unsigned* bucket = (unsigned*)bufB;       // E * 4B (packed dloc<<24|src)

    const int NB = cdiv(N, 256);
    const int GB = cdiv(N, 64);  // mfma gemm grid (64 rows/block)
    (void)NB;

    // ---- CSR build: counting sort, zero global atomics ----
    count_edges<<<NBLK, 512, 0, stream>>>(dst, counts, E);
    scan_pos<<<NBUCK, 512, 0, stream>>>(counts, pos, tot, NBLK);
    scan_base<<<1, 512, 0, stream>>>(tot, base, E);
    place_edges<<<NBLK, 512, 0, stream>>>(src, dst, pos, base, bucket, E);
    build_csr_node<<<NBUCK, 256, 0, stream>>>(bucket, base, offsets, dinv, csr, E);

    // ---- Layer 1: xw1 = x @ W1 (128->64, fp32 in); h1 = LN_ELU(gather + b1) ----
    mfma_gemm<128, 64, false, false, true, false><<<GB, 256, 0, stream>>>(
        x, W1, nullptr, nullptr, nullptr, bufA, N);
    gather64<true><<<cdiv(N, 4), 256, 0, stream>>>(bufA, offsets, csr, dinv, b1, g1, be1, bufB, N);

    // ---- Layer 2 (aggregate-first): a2 = gather(h1); h2 = LN_ELU(a2 @ W2 + b2) ----
    gather64<false><<<cdiv(N, 4), 256, 0, stream>>>(bufB, offsets, csr, dinv, nullptr, nullptr, nullptr, bufA, N);
    mfma_gemm<64, 128, true, true, false, false><<<GB, 256, 0, stream>>>(
        bufA, W2, b2, g2, be2, bufB, N);

    // ---- Layer 3: xw3 = h2 @ W3 (128->64); h3 = LN_ELU(gather + b3) ----
    mfma_gemm<128, 64, false, false, false, false><<<GB, 256, 0, stream>>>(
        bufB, W3, nullptr, nullptr, nullptr, bufA, N);
    gather64<true><<<cdiv(N, 4), 256, 0, stream>>>(bufA, offsets, csr, dinv, b3, g3, be3, bufB, N);

    // ---- lin1: t = LN_ELU(h3 @ lw1 + lb1) (64->32) ----
    mfma_gemm<64, 32, true, true, false, false><<<GB, 256, 0, stream>>>(
        bufB, lw1, lb1, g4, be4, bufA, N);

    // ---- lin2: out = t @ lw2 + lb2 (32->32, fp32 out) ----
    mfma_gemm<32, 32, false, true, false, true><<<GB, 256, 0, stream>>>(
        bufA, lw2, lb2, nullptr, nullptr, out, N);
}

// Round 3
// 377.433 us; speedup vs baseline: 1.3838x; 1.0316x over previous
//
#include <hip/hip_runtime.h>
#include <math.h>

#define N_NODES 100000
#define LN_EPS 1e-5f
#define NBUCK ((N_NODES + 255) / 256)  // 391 buckets of 256 nodes
#define EPB 8192                        // edges per block in count/place

typedef __attribute__((ext_vector_type(8))) short bf16x8;
typedef __attribute__((ext_vector_type(4))) float f32x4;

__device__ __forceinline__ unsigned short f2bf(float f) {
    unsigned int u = __float_as_uint(f);
    return (unsigned short)((u + 0x7FFFu + ((u >> 16) & 1u)) >> 16);
}
__device__ __forceinline__ float bf2f(unsigned short u) {
    return __uint_as_float(((unsigned int)u) << 16);
}

// ======== atomic-free CSR build (counting sort by 256-node bucket) ========

// K1: per-block histogram of dst buckets -> counts[blk][bucket]
__global__ void count_edges(const int* __restrict__ dst, int* __restrict__ counts, int E) {
    __shared__ int hist[NBUCK];
    for (int b = threadIdx.x; b < NBUCK; b += 512) hist[b] = 0;
    __syncthreads();
    int e0 = blockIdx.x * EPB;
#pragma unroll 4
    for (int i = 0; i < EPB / 512; ++i) {
        int e = e0 + i * 512 + (int)threadIdx.x;
        if (e < E) atomicAdd(&hist[((unsigned)dst[e]) >> 8], 1);
    }
    __syncthreads();
    for (int b = threadIdx.x; b < NBUCK; b += 512)
        counts[blockIdx.x * NBUCK + b] = hist[b];
}

// K2: per-bucket exclusive scan across blocks -> pos[blk][bucket], tot[bucket]
__global__ void scan_pos(const int* __restrict__ counts, int* __restrict__ pos,
                         int* __restrict__ tot, int nblk) {
    __shared__ int s[512];
    int b = blockIdx.x, i = threadIdx.x;
    int v = (i < nblk) ? counts[i * NBUCK + b] : 0;
    s[i] = v;
    __syncthreads();
    for (int off = 1; off < 512; off <<= 1) {
        int t = (i >= off) ? s[i - off] : 0;
        __syncthreads();
        s[i] += t;
        __syncthreads();
    }
    if (i < nblk) pos[i * NBUCK + b] = s[i] - v;
    if (i == 511) tot[b] = s[511];
}

// K3: exclusive scan of bucket totals -> base[bucket], base[NBUCK]=E
__global__ void scan_base(const int* __restrict__ tot, int* __restrict__ base, int E) {
    __shared__ int s[512];
    int i = threadIdx.x;
    int v = (i < NBUCK) ? tot[i] : 0;
    s[i] = v;
    __syncthreads();
    for (int off = 1; off < 512; off <<= 1) {
        int t = (i >= off) ? s[i - off] : 0;
        __syncthreads();
        s[i] += t;
        __syncthreads();
    }
    if (i < NBUCK) base[i] = s[i] - v;
    if (i == 0) base[NBUCK] = E;
}

// K4: place edges into per-(block,bucket) disjoint slabs via LDS cursors.
__global__ void place_edges(const int* __restrict__ src, const int* __restrict__ dst,
                            const int* __restrict__ pos, const int* __restrict__ base,
                            unsigned* __restrict__ bucket, int E) {
    __shared__ int lcur[NBUCK];
    for (int b = threadIdx.x; b < NBUCK; b += 512)
        lcur[b] = pos[blockIdx.x * NBUCK + b] + base[b];
    __syncthreads();
    int e0 = blockIdx.x * EPB;
#pragma unroll 4
    for (int i = 0; i < EPB / 512; ++i) {
        int e = e0 + i * 512 + (int)threadIdx.x;
        if (e < E) {
            unsigned d = (unsigned)dst[e];
            unsigned s = (unsigned)src[e];
            int p = atomicAdd(&lcur[d >> 8], 1);
            bucket[p] = ((d & 255u) << 24) | s;
        }
    }
}

// K5: one block per bucket: slab histogram -> degree/dinv/offsets (fused),
// then scatter csr within the block's private 16KB window via LDS cursors.
__global__ void build_csr_node(const unsigned* __restrict__ bucket, const int* __restrict__ base,
                               int* __restrict__ offsets, float* __restrict__ dinv,
                               int* __restrict__ csr, int E) {
    __shared__ int hist[256];
    __shared__ int cur[256];
    int b = blockIdx.x, t = threadIdx.x;
    int r0 = b << 8;
    hist[t] = 0;
    __syncthreads();
    int s0 = base[b], s1 = base[b + 1];
    for (int e = s0 + t; e < s1; e += 256)
        atomicAdd(&hist[bucket[e] >> 24], 1);
    __syncthreads();
    int deg = hist[t];
    for (int off = 1; off < 256; off <<= 1) {
        int tv = (t >= off) ? hist[t - off] : 0;
        __syncthreads();
        hist[t] += tv;
        __syncthreads();
    }
    int excl = hist[t] - deg;  // exclusive scan within bucket
    int node = r0 + t;
    if (node < N_NODES) {
        offsets[node] = s0 + excl;
        dinv[node] = rsqrtf((float)deg + 1.f);
        cur[t] = s0 + excl;
    }
    if (node == N_NODES - 1) offsets[N_NODES] = E;
    __syncthreads();
    for (int e = s0 + t; e < s1; e += 256) {
        unsigned u = bucket[e];
        int p = atomicAdd(&cur[u >> 24], 1);  // LDS atomic, window is L1/L2-hot
        csr[p] = (int)(u & 0xFFFFFFu);
    }
}

// ---------------- MFMA bf16 gemm: Y = X[n,K] @ W[K,OUT] (+bias, +LN+ELU, +dinv row scale) ----
template <int K, int OUT, bool LN, bool BIAS, bool AF32, bool OF32, bool SCALED>
__launch_bounds__(256)
__global__ void mfma_gemm(const void* __restrict__ Xv, const float* __restrict__ W,
                          const float* __restrict__ bias, const float* __restrict__ gamma,
                          const float* __restrict__ beta, void* __restrict__ Yv, int n,
                          const float* __restrict__ dinvp) {
    constexpr int T  = OUT / 16;
    constexpr int KP = K + 8;

    __shared__ __align__(16) unsigned short sWT[OUT * KP];  // W^T bf16
    for (int i = threadIdx.x; i < K * OUT; i += 256) {
        int k = i / OUT, o = i - k * OUT;
        sWT[o * KP + k] = f2bf(W[i]);
    }
    __syncthreads();

    int wv = threadIdx.x >> 6, lane = threadIdx.x & 63;
    int quad = lane >> 4, l16 = lane & 15;
    int m0 = (blockIdx.x * 4 + wv) * 16;
    int rowc = min(m0 + l16, n - 1);

    f32x4 acc[T];
#pragma unroll
    for (int t = 0; t < T; ++t) acc[t] = (f32x4){0.f, 0.f, 0.f, 0.f};

#pragma unroll
    for (int s = 0; s < K / 32; ++s) {
        int koff = s * 32 + quad * 8;
        bf16x8 af;
        if (AF32) {
            const float4* X4 = (const float4*)Xv;
            size_t base = ((size_t)rowc * K + koff) >> 2;
            float4 a0 = X4[base];
            float4 a1 = X4[base + 1];
            af[0] = (short)f2bf(a0.x); af[1] = (short)f2bf(a0.y);
            af[2] = (short)f2bf(a0.z); af[3] = (short)f2bf(a0.w);
            af[4] = (short)f2bf(a1.x); af[5] = (short)f2bf(a1.y);
            af[6] = (short)f2bf(a1.z); af[7] = (short)f2bf(a1.w);
        } else {
            const unsigned short* Xb = (const unsigned short*)Xv;
            af = *(const bf16x8*)(Xb + (size_t)rowc * K + koff);
        }
#pragma unroll
        for (int t = 0; t < T; ++t) {
            const bf16x8 bfrag = *(const bf16x8*)&sWT[(t * 16 + l16) * KP + koff];
            acc[t] = __builtin_amdgcn_mfma_f32_16x16x32_bf16(af, bfrag, acc[t], 0, 0, 0);
        }
    }

    float bj[T], gj[T], btj[T];
#pragma unroll
    for (int t = 0; t < T; ++t) {
        int c = t * 16 + l16;
        bj[t]  = BIAS ? bias[c] : 0.f;
        gj[t]  = LN ? gamma[c] : 1.f;
        btj[t] = LN ? beta[c] : 0.f;
    }

    float* Yf = (float*)Yv;
    unsigned short* Yb = (unsigned short*)Yv;

    if (LN) {
        float s[4] = {0.f, 0.f, 0.f, 0.f}, sq[4] = {0.f, 0.f, 0.f, 0.f};
#pragma unroll
        for (int t = 0; t < T; ++t)
#pragma unroll
            for (int r = 0; r < 4; ++r) {
                float v = acc[t][r] + bj[t];
                s[r] += v;
                sq[r] += v * v;
            }
#pragma unroll
        for (int off = 1; off < 16; off <<= 1)
#pragma unroll
            for (int r = 0; r < 4; ++r) {
                s[r] += __shfl_xor(s[r], off, 64);
                sq[r] += __shfl_xor(sq[r], off, 64);
            }
        float mu[4], rs[4];
#pragma unroll
        for (int r = 0; r < 4; ++r) {
            mu[r] = s[r] / OUT;
            float var = sq[r] / OUT - mu[r] * mu[r];
            rs[r] = rsqrtf(var + LN_EPS);
        }
#pragma unroll
        for (int r = 0; r < 4; ++r) {
            int rowg = m0 + quad * 4 + r;
            if (rowg < n) {
                float dv = SCALED ? dinvp[rowg] : 1.f;
#pragma unroll
                for (int t = 0; t < T; ++t) {
                    float y = (acc[t][r] + bj[t] - mu[r]) * rs[r] * gj[t] + btj[t];
                    y = y > 0.f ? y : expm1f(y);
                    if (SCALED) y *= dv;
                    size_t idx = (size_t)rowg * OUT + t * 16 + l16;
                    if (OF32) Yf[idx] = y; else Yb[idx] = f2bf(y);
                }
            }
        }
    } else {
#pragma unroll
        for (int r = 0; r < 4; ++r) {
            int rowg = m0 + quad * 4 + r;
            if (rowg < n) {
                float dv = SCALED ? dinvp[rowg] : 1.f;
#pragma unroll
                for (int t = 0; t < T; ++t) {
                    float y = acc[t][r] + bj[t];
                    if (SCALED) y *= dv;
                    size_t idx = (size_t)rowg * OUT + t * 16 + l16;
                    if (OF32) Yf[idx] = y; else Yb[idx] = f2bf(y);
                }
            }
        }
    }
}

// ---------------- gather v3: readlane + scalar-base row sum ----------------
// Input xs is PRE-SCALED by dinv[row] at the producer, so:
//   out = dinv[node] * (sum_{s in N(node)} xs[s] + xs[node])
// One wave per node, one feature per lane (64 feat, 2B/lane = 128B/row,
// fully coalesced). Edge list is wave-uniform: vector-load 64 src ids, then
// v_readlane puts each src in an SGPR -> row address math on the SALU pipe,
// loads are global_load_ushort v, v_off, s[base]. No LDS ops, no per-edge
// weight gather, FMA->ADD. 4 independent accumulators keep 4 rows in flight.
template <bool LN, bool SCALEOUT>
__global__ void gather_rl(const unsigned short* __restrict__ xs, const int* __restrict__ offsets,
                          const int* __restrict__ csr_src, const float* __restrict__ dinv,
                          const float* __restrict__ bias, const float* __restrict__ gamma,
                          const float* __restrict__ beta, unsigned short* __restrict__ out, int n) {
    int wave = threadIdx.x >> 6;
    int lane = threadIdx.x & 63;
    int node = blockIdx.x * (blockDim.x >> 6) + wave;
    if (node >= n) return;
    int beg = offsets[node], end = offsets[node + 1];

    float a0 = 0.f, a1 = 0.f, a2 = 0.f, a3 = 0.f;
    for (int base = beg; base < end; base += 64) {
        int m = min(64, end - base);
        int myS = (lane < m) ? csr_src[base + lane] : 0;
        int k = 0;
        for (; k + 4 <= m; k += 4) {
            int s0 = __builtin_amdgcn_readlane(myS, k);
            int s1 = __builtin_amdgcn_readlane(myS, k + 1);
            int s2 = __builtin_amdgcn_readlane(myS, k + 2);
            int s3 = __builtin_amdgcn_readlane(myS, k + 3);
            unsigned short v0 = xs[((size_t)s0 << 6) + lane];
            unsigned short v1 = xs[((size_t)s1 << 6) + lane];
            unsigned short v2 = xs[((size_t)s2 << 6) + lane];
            unsigned short v3 = xs[((size_t)s3 << 6) + lane];
            a0 += bf2f(v0);
            a1 += bf2f(v1);
            a2 += bf2f(v2);
            a3 += bf2f(v3);
        }
        for (; k < m; ++k) {
            int s0 = __builtin_amdgcn_readlane(myS, k);
            a0 += bf2f(xs[((size_t)s0 << 6) + lane]);
        }
    }

    float dd = dinv[node];
    float self = bf2f(xs[((size_t)node << 6) + lane]);
    float y = (a0 + a1 + a2 + a3 + self) * dd;

    if (!LN) {
        out[((size_t)node << 6) + lane] = f2bf(y);
        return;
    }
    float yb = y + bias[lane];
    float s = yb, sq = yb * yb;
#pragma unroll
    for (int off = 1; off < 64; off <<= 1) {
        s += __shfl_xor(s, off, 64);
        sq += __shfl_xor(sq, off, 64);
    }
    float mu = s * (1.f / 64.f);
    float var = sq * (1.f / 64.f) - mu * mu;
    float rs = rsqrtf(var + LN_EPS);
    float z = (yb - mu) * rs * gamma[lane] + beta[lane];
    z = z > 0.f ? z : expm1f(z);
    if (SCALEOUT) z *= dd;  // produce xs for the next gather
    out[((size_t)node << 6) + lane] = f2bf(z);
}

extern "C" void kernel_launch(void* const* d_in, const int* in_sizes, int n_in,
                              void* d_out, int out_size, void* d_ws, size_t ws_size,
                              hipStream_t stream) {
    const float* x  = (const float*)d_in[0];
    const int* ei   = (const int*)d_in[1];
    const float* W1 = (const float*)d_in[2];
    const float* b1 = (const float*)d_in[3];
    const float* g1 = (const float*)d_in[4];
    const float* be1= (const float*)d_in[5];
    const float* W2 = (const float*)d_in[6];
    const float* b2 = (const float*)d_in[7];
    const float* g2 = (const float*)d_in[8];
    const float* be2= (const float*)d_in[9];
    const float* W3 = (const float*)d_in[10];
    const float* b3 = (const float*)d_in[11];
    const float* g3 = (const float*)d_in[12];
    const float* be3= (const float*)d_in[13];
    const float* lw1= (const float*)d_in[14];
    const float* lb1= (const float*)d_in[15];
    const float* g4 = (const float*)d_in[16];
    const float* be4= (const float*)d_in[17];
    const float* lw2= (const float*)d_in[18];
    const float* lb2= (const float*)d_in[19];
    float* out = (float*)d_out;

    const int E = in_sizes[1] / 2;
    const int* src = ei;
    const int* dst = ei + E;
    const int N = N_NODES;

    // workspace layout (intermediates in bf16)
    unsigned short* bufA = (unsigned short*)d_ws;       // N*128 bf16
    unsigned short* bufB = bufA + (size_t)N * 128;      // N*128 bf16
    float* dinv    = (float*)(bufB + (size_t)N * 128);  // N f32
    int*   offsets = (int*)(dinv + N);                  // N+1
    int*   csr     = offsets + N + 1;                   // E
    int*   tot     = csr + E;                           // NBUCK
    int*   base    = tot + NBUCK;                       // NBUCK+1

    auto cdiv = [](long long a, long long b) { return (int)((a + b - 1) / b); };
    const int NBLK = cdiv(E, EPB);  // 196 for E=1.6M (must be <= 512)

    // counts/pos alias bufA (dead until gemm1); bucket aliases bufB (dead
    // until gather1 writes it).
    int* counts = (int*)bufA;                 // NBLK*NBUCK ints (~300KB)
    int* pos    = counts + (size_t)NBLK * NBUCK;
    unsigned* bucket = (unsigned*)bufB;       // E * 4B (packed dloc<<24|src)

    const int GB = cdiv(N, 64);  // mfma gemm grid (64 rows/block)

    // ---- CSR build: counting sort, zero global atomics ----
    count_edges<<<NBLK, 512, 0, stream>>>(dst, counts, E);
    scan_pos<<<NBUCK, 512, 0, stream>>>(counts, pos, tot, NBLK);
    scan_base<<<1, 512, 0, stream>>>(tot, base, E);
    place_edges<<<NBLK, 512, 0, stream>>>(src, dst, pos, base, bucket, E);
    build_csr_node<<<NBUCK, 256, 0, stream>>>(bucket, base, offsets, dinv, csr, E);

    // ---- Layer 1: xs0 = dinv*(x @ W1) (128->64, fp32 in); h1s = dinv*LN_ELU(gather + b1) ----
    mfma_gemm<128, 64, false, false, true, false, true><<<GB, 256, 0, stream>>>(
        x, W1, nullptr, nullptr, nullptr, bufA, N, dinv);
    gather_rl<true, true><<<cdiv(N, 4), 256, 0, stream>>>(bufA, offsets, csr, dinv, b1, g1, be1, bufB, N);

    // ---- Layer 2 (aggregate-first): a2 = gather(h1s); h2 = LN_ELU(a2 @ W2 + b2) ----
    gather_rl<false, false><<<cdiv(N, 4), 256, 0, stream>>>(bufB, offsets, csr, dinv, nullptr, nullptr, nullptr, bufA, N);
    mfma_gemm<64, 128, true, true, false, false, false><<<GB, 256, 0, stream>>>(
        bufA, W2, b2, g2, be2, bufB, N, nullptr);

    // ---- Layer 3: xs2 = dinv*(h2 @ W3) (128->64); h3 = LN_ELU(gather + b3) ----
    mfma_gemm<128, 64, false, false, false, false, true><<<GB, 256, 0, stream>>>(
        bufB, W3, nullptr, nullptr, nullptr, bufA, N, dinv);
    gather_rl<true, false><<<cdiv(N, 4), 256, 0, stream>>>(bufA, offsets, csr, dinv, b3, g3, be3, bufB, N);

    // ---- lin1: t = LN_ELU(h3 @ lw1 + lb1) (64->32) ----
    mfma_gemm<64, 32, true, true, false, false, false><<<GB, 256, 0, stream>>>(
        bufB, lw1, lb1, g4, be4, bufA, N, nullptr);

    // ---- lin2: out = t @ lw2 + lb2 (32->32, fp32 out) ----
    mfma_gemm<32, 32, false, true, false, true, false><<<GB, 256, 0, stream>>>(
        bufA, lw2, lb2, nullptr, nullptr, out, N, nullptr);
}